// Round 1
// baseline (406.414 us; speedup 1.0000x reference)
//
#include <hip/hip_runtime.h>
#include <hip/hip_bf16.h>
#include <math.h>

#define D_MODEL 1024
#define NHEADS  16
#define HDIM    64
#define BATCH   4
#define SEQ     2048

typedef __attribute__((ext_vector_type(8))) short short8;
typedef __attribute__((ext_vector_type(4))) float f32x4;

__device__ __forceinline__ short bf16_of(float f) {
  __hip_bfloat16 h = __float2bfloat16(f);
  return *reinterpret_cast<short*>(&h);
}

// ---------------- fp32 -> bf16 convert (weights) ----------------
__global__ __launch_bounds__(256) void cvt_f32_bf16(const float* __restrict__ src,
                                                    short* __restrict__ dst, int n4) {
  int i = blockIdx.x * blockDim.x + threadIdx.x;
  int stride = gridDim.x * blockDim.x;
  for (; i < n4; i += stride) {
    float4 v = reinterpret_cast<const float4*>(src)[i];
    unsigned p0 = (unsigned)(unsigned short)bf16_of(v.x) |
                  ((unsigned)(unsigned short)bf16_of(v.y) << 16);
    unsigned p1 = (unsigned)(unsigned short)bf16_of(v.z) |
                  ((unsigned)(unsigned short)bf16_of(v.w) << 16);
    reinterpret_cast<uint2*>(dst)[i] = make_uint2(p0, p1);
  }
}

// ---------------- GEMM: Out[M,N] = A[M,K] @ Bw[N,K]^T + bias ----------------
// 128x128 tile, 256 threads = 4 waves (2x2), each wave 64x64 via 4x4 MFMA frags.
template<bool A_F32, bool OUT_F32>
__global__ __launch_bounds__(256) void gemm_bt(
    const void* __restrict__ Aptr, const short* __restrict__ Bw,
    const float* __restrict__ bias, void* __restrict__ Out,
    int M, int N, int K)
{
  const int tid  = threadIdx.x;
  const int lane = tid & 63;
  const int wave = tid >> 6;
  const int m0 = blockIdx.y * 128;
  const int n0 = blockIdx.x * 128;
  const int wm = (wave >> 1) * 64;
  const int wn = (wave & 1) * 64;

  __shared__ short As[128][40];   // BK=32 + 8 pad (bank spread)
  __shared__ short Bs[128][40];

  f32x4 acc[4][4];
#pragma unroll
  for (int m = 0; m < 4; ++m)
#pragma unroll
    for (int n = 0; n < 4; ++n)
      acc[m][n] = (f32x4){0.f, 0.f, 0.f, 0.f};

  for (int k0 = 0; k0 < K; k0 += 32) {
    if constexpr (A_F32) {
      const float* A = (const float*)Aptr;
#pragma unroll
      for (int i = 0; i < 4; ++i) {
        int c = tid + i * 256;          // 1024 chunks of float4
        int row = c >> 3;
        int c4 = (c & 7) * 4;
        float4 v = *reinterpret_cast<const float4*>(&A[(size_t)(m0 + row) * K + k0 + c4]);
        unsigned p0 = (unsigned)(unsigned short)bf16_of(v.x) |
                      ((unsigned)(unsigned short)bf16_of(v.y) << 16);
        unsigned p1 = (unsigned)(unsigned short)bf16_of(v.z) |
                      ((unsigned)(unsigned short)bf16_of(v.w) << 16);
        *reinterpret_cast<uint2*>(&As[row][c4]) = make_uint2(p0, p1);
      }
    } else {
      const short* A = (const short*)Aptr;
#pragma unroll
      for (int i = 0; i < 2; ++i) {
        int c = tid + i * 256;          // 512 chunks of 8 bf16
        int row = c >> 2;
        int c8 = (c & 3) * 8;
        *reinterpret_cast<uint4*>(&As[row][c8]) =
            *reinterpret_cast<const uint4*>(&A[(size_t)(m0 + row) * K + k0 + c8]);
      }
    }
#pragma unroll
    for (int i = 0; i < 2; ++i) {
      int c = tid + i * 256;
      int row = c >> 2;
      int c8 = (c & 3) * 8;
      *reinterpret_cast<uint4*>(&Bs[row][c8]) =
          *reinterpret_cast<const uint4*>(&Bw[(size_t)(n0 + row) * K + k0 + c8]);
    }
    __syncthreads();

    short8 afr[4], bfr[4];
#pragma unroll
    for (int m = 0; m < 4; ++m)
      afr[m] = *reinterpret_cast<const short8*>(&As[wm + m * 16 + (lane & 15)][(lane >> 4) * 8]);
#pragma unroll
    for (int n = 0; n < 4; ++n)
      bfr[n] = *reinterpret_cast<const short8*>(&Bs[wn + n * 16 + (lane & 15)][(lane >> 4) * 8]);
#pragma unroll
    for (int m = 0; m < 4; ++m)
#pragma unroll
      for (int n = 0; n < 4; ++n)
        acc[m][n] = __builtin_amdgcn_mfma_f32_16x16x32_bf16(afr[m], bfr[n], acc[m][n], 0, 0, 0);
    __syncthreads();
  }

  // epilogue: D layout col=lane&15, row=(lane>>4)*4+r
#pragma unroll
  for (int n = 0; n < 4; ++n) {
    int col = n0 + wn + n * 16 + (lane & 15);
    float bv = bias[col];
#pragma unroll
    for (int m = 0; m < 4; ++m) {
      int rowb = m0 + wm + m * 16 + (lane >> 4) * 4;
#pragma unroll
      for (int r = 0; r < 4; ++r) {
        float val = acc[m][n][r] + bv;
        if constexpr (OUT_F32)
          ((float*)Out)[(size_t)(rowb + r) * N + col] = val;
        else
          ((short*)Out)[(size_t)(rowb + r) * N + col] = bf16_of(val);
      }
    }
  }
}

// ---------------- per-head V transpose: V[B,S,D] -> VT[B,H,HDIM,SEQ] ----------------
__global__ __launch_bounds__(256) void transpose_v(const short* __restrict__ V,
                                                   short* __restrict__ VT) {
  int st = blockIdx.x;              // 64-row s tile
  int bh = blockIdx.y;
  int b = bh >> 4, h = bh & 15;
  __shared__ short T[64][72];
  int tid = threadIdx.x;
#pragma unroll
  for (int i = 0; i < 2; ++i) {
    int c = tid + i * 256;          // 512 chunks of 8 bf16
    int srow = c >> 3;
    int d8 = (c & 7) * 8;
    *reinterpret_cast<uint4*>(&T[srow][d8]) = *reinterpret_cast<const uint4*>(
        &V[((size_t)b * SEQ + st * 64 + srow) * D_MODEL + h * HDIM + d8]);
  }
  __syncthreads();
#pragma unroll
  for (int i = 0; i < 2; ++i) {
    int c = tid + i * 256;
    int drow = c >> 3;
    int s8 = (c & 7) * 8;
    __align__(16) short tmp[8];
#pragma unroll
    for (int j = 0; j < 8; ++j) tmp[j] = T[s8 + j][drow];
    *reinterpret_cast<uint4*>(
        &VT[(((size_t)b * NHEADS + h) * HDIM + drow) * SEQ + st * 64 + s8]) =
        *reinterpret_cast<uint4*>(tmp);
  }
}

// ---------------- flash attention ----------------
// grid: (SEQ/64, B*H). 256 thr = 4 waves; each wave owns 16 query rows.
__global__ __launch_bounds__(256) void attn_fwd(
    const short* __restrict__ Q,   // [B,S,D] bf16
    const short* __restrict__ Kg,  // [B,S,D] bf16
    const short* __restrict__ VT,  // [B,H,HDIM,SEQ] bf16
    short* __restrict__ Oc)        // [B,S,D] bf16 (concat)
{
  const int tid = threadIdx.x, lane = tid & 63, wave = tid >> 6;
  const int q0 = blockIdx.x * 64;
  const int bh = blockIdx.y, b = bh >> 4, h = bh & 15;

  __shared__ short Ks[64][72];     // [key][d]
  __shared__ short Vs[64][72];     // [d][key]
  __shared__ short Ps[4][16][72];  // per-wave P tile [q][key]

  // Q fragments in registers (A-operand: row=lane&15, k contiguous 8 at (lane>>4)*8)
  short8 qfr[2];
  {
    int qrow = q0 + wave * 16 + (lane & 15);
    const short* qp = &Q[((size_t)b * SEQ + qrow) * D_MODEL + h * HDIM + (lane >> 4) * 8];
    qfr[0] = *reinterpret_cast<const short8*>(qp);
    qfr[1] = *reinterpret_cast<const short8*>(qp + 32);
  }

  f32x4 o[4];
#pragma unroll
  for (int nb = 0; nb < 4; ++nb) o[nb] = (f32x4){0.f, 0.f, 0.f, 0.f};
  float runM[4], runL[4];
#pragma unroll
  for (int r = 0; r < 4; ++r) { runM[r] = -INFINITY; runL[r] = 0.f; }

  for (int k0 = 0; k0 < SEQ; k0 += 64) {
    // stage K tile [64 keys][64 d]
#pragma unroll
    for (int i = 0; i < 2; ++i) {
      int c = tid + i * 256;
      int row = c >> 3, d8 = (c & 7) * 8;
      *reinterpret_cast<uint4*>(&Ks[row][d8]) = *reinterpret_cast<const uint4*>(
          &Kg[((size_t)b * SEQ + k0 + row) * D_MODEL + h * HDIM + d8]);
    }
    // stage V^T tile [64 d][64 keys]
#pragma unroll
    for (int i = 0; i < 2; ++i) {
      int c = tid + i * 256;
      int drow = c >> 3, s8 = (c & 7) * 8;
      *reinterpret_cast<uint4*>(&Vs[drow][s8]) = *reinterpret_cast<const uint4*>(
          &VT[(((size_t)b * NHEADS + h) * HDIM + drow) * SEQ + k0 + s8]);
    }
    __syncthreads();

    // scores = Q @ K^T / 8 : 16q x 64keys per wave
    f32x4 s[4];
#pragma unroll
    for (int n = 0; n < 4; ++n) {
      short8 b0 = *reinterpret_cast<const short8*>(&Ks[n * 16 + (lane & 15)][(lane >> 4) * 8]);
      short8 b1 = *reinterpret_cast<const short8*>(&Ks[n * 16 + (lane & 15)][32 + (lane >> 4) * 8]);
      f32x4 z = (f32x4){0.f, 0.f, 0.f, 0.f};
      z = __builtin_amdgcn_mfma_f32_16x16x32_bf16(qfr[0], b0, z, 0, 0, 0);
      z = __builtin_amdgcn_mfma_f32_16x16x32_bf16(qfr[1], b1, z, 0, 0, 0);
      s[n] = z * 0.125f;
    }

    // online softmax (rows live at (lane>>4)*4+r; cols across 16-lane group)
    float tm[4];
#pragma unroll
    for (int r = 0; r < 4; ++r)
      tm[r] = fmaxf(fmaxf(s[0][r], s[1][r]), fmaxf(s[2][r], s[3][r]));
#pragma unroll
    for (int mask = 1; mask < 16; mask <<= 1)
#pragma unroll
      for (int r = 0; r < 4; ++r) tm[r] = fmaxf(tm[r], __shfl_xor(tm[r], mask));

    float nm[4], al[4], ts[4];
#pragma unroll
    for (int r = 0; r < 4; ++r) {
      nm[r] = fmaxf(runM[r], tm[r]);
      al[r] = __expf(runM[r] - nm[r]);
      ts[r] = 0.f;
    }
#pragma unroll
    for (int n = 0; n < 4; ++n)
#pragma unroll
      for (int r = 0; r < 4; ++r) {
        float p = __expf(s[n][r] - nm[r]);
        s[n][r] = p;
        ts[r] += p;
      }
#pragma unroll
    for (int mask = 1; mask < 16; mask <<= 1)
#pragma unroll
      for (int r = 0; r < 4; ++r) ts[r] += __shfl_xor(ts[r], mask);
#pragma unroll
    for (int r = 0; r < 4; ++r) {
      runL[r] = runL[r] * al[r] + ts[r];
      runM[r] = nm[r];
    }

    // write P (bf16) to per-wave LDS, rescale O
#pragma unroll
    for (int n = 0; n < 4; ++n)
#pragma unroll
      for (int r = 0; r < 4; ++r)
        Ps[wave][(lane >> 4) * 4 + r][n * 16 + (lane & 15)] = bf16_of(s[n][r]);
#pragma unroll
    for (int nb = 0; nb < 4; ++nb)
#pragma unroll
      for (int r = 0; r < 4; ++r) o[nb][r] *= al[r];
    __syncthreads();   // drain P writes (cross-lane) before A-frag reads

    // O += P @ V : A-operand from Ps, B-operand from Vs
    short8 pa0 = *reinterpret_cast<const short8*>(&Ps[wave][lane & 15][(lane >> 4) * 8]);
    short8 pa1 = *reinterpret_cast<const short8*>(&Ps[wave][lane & 15][32 + (lane >> 4) * 8]);
#pragma unroll
    for (int nb = 0; nb < 4; ++nb) {
      short8 bv0 = *reinterpret_cast<const short8*>(&Vs[nb * 16 + (lane & 15)][(lane >> 4) * 8]);
      short8 bv1 = *reinterpret_cast<const short8*>(&Vs[nb * 16 + (lane & 15)][32 + (lane >> 4) * 8]);
      o[nb] = __builtin_amdgcn_mfma_f32_16x16x32_bf16(pa0, bv0, o[nb], 0, 0, 0);
      o[nb] = __builtin_amdgcn_mfma_f32_16x16x32_bf16(pa1, bv1, o[nb], 0, 0, 0);
    }
    __syncthreads();   // protect Ks/Vs/Ps for next iteration
  }

  // epilogue: normalize and store concat layout [B,S,D]
#pragma unroll
  for (int nb = 0; nb < 4; ++nb)
#pragma unroll
    for (int r = 0; r < 4; ++r) {
      int qrow = q0 + wave * 16 + (lane >> 4) * 4 + r;
      int col = h * HDIM + nb * 16 + (lane & 15);
      Oc[((size_t)b * SEQ + qrow) * D_MODEL + col] = bf16_of(o[nb][r] / runL[r]);
    }
}

// ---------------- launch ----------------
extern "C" void kernel_launch(void* const* d_in, const int* in_sizes, int n_in,
                              void* d_out, int out_size, void* d_ws, size_t ws_size,
                              hipStream_t stream)
{
  const float* q  = (const float*)d_in[0];
  const float* k  = (const float*)d_in[1];
  const float* v  = (const float*)d_in[2];
  const float* Wq = (const float*)d_in[3];
  const float* bq = (const float*)d_in[4];
  const float* Wk = (const float*)d_in[5];
  const float* bk = (const float*)d_in[6];
  const float* Wv = (const float*)d_in[7];
  const float* bv = (const float*)d_in[8];
  const float* Wo = (const float*)d_in[9];
  const float* bo = (const float*)d_in[10];

  char* ws = (char*)d_ws;
  const size_t MB = 1ull << 20;
  short* Wq_b = (short*)(ws + 0 * MB);
  short* Wk_b = (short*)(ws + 2 * MB);
  short* Wv_b = (short*)(ws + 4 * MB);
  short* Wo_b = (short*)(ws + 6 * MB);
  short* Qb   = (short*)(ws + 8 * MB);
  short* Kb   = (short*)(ws + 24 * MB);
  short* Vb   = (short*)(ws + 40 * MB);
  short* VTb  = (short*)(ws + 56 * MB);
  short* Ac   = (short*)(ws + 40 * MB);   // aliases Vb (dead after transpose)

  const int M = BATCH * SEQ;
  int n4w = (D_MODEL * D_MODEL) / 4;
  cvt_f32_bf16<<<512, 256, 0, stream>>>(Wq, Wq_b, n4w);
  cvt_f32_bf16<<<512, 256, 0, stream>>>(Wk, Wk_b, n4w);
  cvt_f32_bf16<<<512, 256, 0, stream>>>(Wv, Wv_b, n4w);
  cvt_f32_bf16<<<512, 256, 0, stream>>>(Wo, Wo_b, n4w);

  dim3 gg(D_MODEL / 128, M / 128);
  gemm_bt<true, false><<<gg, 256, 0, stream>>>(q, Wq_b, bq, Qb, M, D_MODEL, D_MODEL);
  gemm_bt<true, false><<<gg, 256, 0, stream>>>(k, Wk_b, bk, Kb, M, D_MODEL, D_MODEL);
  gemm_bt<true, false><<<gg, 256, 0, stream>>>(v, Wv_b, bv, Vb, M, D_MODEL, D_MODEL);

  transpose_v<<<dim3(SEQ / 64, BATCH * NHEADS), 256, 0, stream>>>(Vb, VTb);

  attn_fwd<<<dim3(SEQ / 64, BATCH * NHEADS), 256, 0, stream>>>(Qb, Kb, VTb, Ac);

  gemm_bt<false, true><<<gg, 256, 0, stream>>>(Ac, Wo_b, bo, (float*)d_out, M, D_MODEL, D_MODEL);
}

// Round 2
// 314.925 us; speedup vs baseline: 1.2905x; 1.2905x over previous
//
#include <hip/hip_runtime.h>
#include <hip/hip_bf16.h>
#include <math.h>

#define D_MODEL 1024
#define NHEADS  16
#define HDIM    64
#define BATCH   4
#define SEQ     2048

typedef __attribute__((ext_vector_type(8))) short short8;
typedef __attribute__((ext_vector_type(4))) float f32x4;

__device__ __forceinline__ short bf16_of(float f) {
  __hip_bfloat16 h = __float2bfloat16(f);
  return *reinterpret_cast<short*>(&h);
}

__device__ __forceinline__ unsigned pack2(float lo, float hi) {
  return (unsigned)(unsigned short)bf16_of(lo) |
         ((unsigned)(unsigned short)bf16_of(hi) << 16);
}

__device__ __forceinline__ short8 mk_frag(unsigned a, unsigned b, unsigned c, unsigned d) {
  union { unsigned u[4]; short8 s; } t;
  t.u[0] = a; t.u[1] = b; t.u[2] = c; t.u[3] = d;
  return t.s;
}

// ---------------- fp32 -> bf16 convert (weights) ----------------
__global__ __launch_bounds__(256) void cvt_f32_bf16(const float* __restrict__ src,
                                                    short* __restrict__ dst, int n4) {
  int i = blockIdx.x * blockDim.x + threadIdx.x;
  int stride = gridDim.x * blockDim.x;
  for (; i < n4; i += stride) {
    float4 v = reinterpret_cast<const float4*>(src)[i];
    unsigned p0 = pack2(v.x, v.y);
    unsigned p1 = pack2(v.z, v.w);
    reinterpret_cast<uint2*>(dst)[i] = make_uint2(p0, p1);
  }
}

// ---------------- GEMM: Out[M,N] = A[M,K] @ Bw[N,K]^T + bias ----------------
template<bool A_F32, bool OUT_F32>
__global__ __launch_bounds__(256) void gemm_bt(
    const void* __restrict__ Aptr, const short* __restrict__ Bw,
    const float* __restrict__ bias, void* __restrict__ Out,
    int M, int N, int K)
{
  const int tid  = threadIdx.x;
  const int lane = tid & 63;
  const int wave = tid >> 6;
  const int m0 = blockIdx.y * 128;
  const int n0 = blockIdx.x * 128;
  const int wm = (wave >> 1) * 64;
  const int wn = (wave & 1) * 64;

  __shared__ short As[128][40];
  __shared__ short Bs[128][40];

  f32x4 acc[4][4];
#pragma unroll
  for (int m = 0; m < 4; ++m)
#pragma unroll
    for (int n = 0; n < 4; ++n)
      acc[m][n] = (f32x4){0.f, 0.f, 0.f, 0.f};

  for (int k0 = 0; k0 < K; k0 += 32) {
    if constexpr (A_F32) {
      const float* A = (const float*)Aptr;
#pragma unroll
      for (int i = 0; i < 4; ++i) {
        int c = tid + i * 256;
        int row = c >> 3;
        int c4 = (c & 7) * 4;
        float4 v = *reinterpret_cast<const float4*>(&A[(size_t)(m0 + row) * K + k0 + c4]);
        *reinterpret_cast<uint2*>(&As[row][c4]) = make_uint2(pack2(v.x, v.y), pack2(v.z, v.w));
      }
    } else {
      const short* A = (const short*)Aptr;
#pragma unroll
      for (int i = 0; i < 2; ++i) {
        int c = tid + i * 256;
        int row = c >> 2;
        int c8 = (c & 3) * 8;
        *reinterpret_cast<uint4*>(&As[row][c8]) =
            *reinterpret_cast<const uint4*>(&A[(size_t)(m0 + row) * K + k0 + c8]);
      }
    }
#pragma unroll
    for (int i = 0; i < 2; ++i) {
      int c = tid + i * 256;
      int row = c >> 2;
      int c8 = (c & 3) * 8;
      *reinterpret_cast<uint4*>(&Bs[row][c8]) =
          *reinterpret_cast<const uint4*>(&Bw[(size_t)(n0 + row) * K + k0 + c8]);
    }
    __syncthreads();

    short8 afr[4], bfr[4];
#pragma unroll
    for (int m = 0; m < 4; ++m)
      afr[m] = *reinterpret_cast<const short8*>(&As[wm + m * 16 + (lane & 15)][(lane >> 4) * 8]);
#pragma unroll
    for (int n = 0; n < 4; ++n)
      bfr[n] = *reinterpret_cast<const short8*>(&Bs[wn + n * 16 + (lane & 15)][(lane >> 4) * 8]);
#pragma unroll
    for (int m = 0; m < 4; ++m)
#pragma unroll
      for (int n = 0; n < 4; ++n)
        acc[m][n] = __builtin_amdgcn_mfma_f32_16x16x32_bf16(afr[m], bfr[n], acc[m][n], 0, 0, 0);
    __syncthreads();
  }

#pragma unroll
  for (int n = 0; n < 4; ++n) {
    int col = n0 + wn + n * 16 + (lane & 15);
    float bv = bias[col];
#pragma unroll
    for (int m = 0; m < 4; ++m) {
      int rowb = m0 + wm + m * 16 + (lane >> 4) * 4;
#pragma unroll
      for (int r = 0; r < 4; ++r) {
        float val = acc[m][n][r] + bv;
        if constexpr (OUT_F32)
          ((float*)Out)[(size_t)(rowb + r) * N + col] = val;
        else
          ((short*)Out)[(size_t)(rowb + r) * N + col] = bf16_of(val);
      }
    }
  }
}

// ---------------- per-head V transpose: V[B,S,D] -> VT[B,H,HDIM,SEQ] ----------------
__global__ __launch_bounds__(256) void transpose_v(const short* __restrict__ V,
                                                   short* __restrict__ VT) {
  int st = blockIdx.x;
  int bh = blockIdx.y;
  int b = bh >> 4, h = bh & 15;
  __shared__ short T[64][72];
  int tid = threadIdx.x;
#pragma unroll
  for (int i = 0; i < 2; ++i) {
    int c = tid + i * 256;
    int srow = c >> 3;
    int d8 = (c & 7) * 8;
    *reinterpret_cast<uint4*>(&T[srow][d8]) = *reinterpret_cast<const uint4*>(
        &V[((size_t)b * SEQ + st * 64 + srow) * D_MODEL + h * HDIM + d8]);
  }
  __syncthreads();
#pragma unroll
  for (int i = 0; i < 2; ++i) {
    int c = tid + i * 256;
    int drow = c >> 3;
    int s8 = (c & 7) * 8;
    __align__(16) short tmp[8];
#pragma unroll
    for (int j = 0; j < 8; ++j) tmp[j] = T[s8 + j][drow];
    *reinterpret_cast<uint4*>(
        &VT[(((size_t)b * NHEADS + h) * HDIM + drow) * SEQ + st * 64 + s8]) =
        *reinterpret_cast<uint4*>(tmp);
  }
}

// ---------------- flash attention, swapped-QK^T, P lane-local ----------------
// grid: (SEQ/64, B*H). 256 thr = 4 waves; each wave owns 16 query rows.
// D of QK: lane holds S^T[key][q]: q = lane&15, keys {16n + 4g + r}.
// PV uses key-permutation pi(kh, 8g+j) = 32kh + 16(j>>2) + 4g + (j&3) so the
// lane's own P registers form its B-fragment; V^T staged into LDS with pi applied.
__global__ __launch_bounds__(256) void attn_fwd(
    const short* __restrict__ Q,   // [B,S,D] bf16
    const short* __restrict__ Kg,  // [B,S,D] bf16
    const short* __restrict__ VT,  // [B,H,HDIM,SEQ] bf16
    short* __restrict__ Oc)        // [B,S,D] bf16 (concat)
{
  const int tid = threadIdx.x, lane = tid & 63, wave = tid >> 6;
  const int qi = lane & 15, g = lane >> 4;
  const int q0 = blockIdx.x * 64;
  const int bh = blockIdx.y, b = bh >> 4, h = bh & 15;

  __shared__ short Ks[2][64][72];   // [buf][key][d]
  __shared__ short Vs[2][64][72];   // [buf][d][pi(key)]

  // Q fragment (B-operand: col=lane&15=q, k=d contiguous at g*8)
  short8 qfr[2];
  {
    int qrow = q0 + wave * 16 + qi;
    const short* qp = &Q[((size_t)b * SEQ + qrow) * D_MODEL + h * HDIM + g * 8];
    qfr[0] = *reinterpret_cast<const short8*>(qp);
    qfr[1] = *reinterpret_cast<const short8*>(qp + 32);
  }

  const size_t kbase = ((size_t)b * SEQ) * D_MODEL + h * HDIM;
  const size_t vbase = ((size_t)bh * HDIM) * SEQ;

  f32x4 o[4];
#pragma unroll
  for (int db = 0; db < 4; ++db) o[db] = (f32x4){0.f, 0.f, 0.f, 0.f};
  float runM = -INFINITY, runL = 0.f;

  // prologue: stage tile 0 into buffer 0
#pragma unroll
  for (int i = 0; i < 2; ++i) {
    int c = tid + i * 256;
    int row = c >> 3, sub = c & 7;
    uint4 kv = *reinterpret_cast<const uint4*>(&Kg[kbase + (size_t)row * D_MODEL + sub * 8]);
    *reinterpret_cast<uint4*>(&Ks[0][row][sub * 8]) = kv;
    uint4 vv = *reinterpret_cast<const uint4*>(&VT[vbase + (size_t)row * SEQ + sub * 8]);
    int posA = 32 * (sub >> 2) + 16 * (sub & 1) + 4 * ((sub >> 1) & 1);
    *reinterpret_cast<uint2*>(&Vs[0][row][posA])     = make_uint2(vv.x, vv.y);
    *reinterpret_cast<uint2*>(&Vs[0][row][posA + 8]) = make_uint2(vv.z, vv.w);
  }
  __syncthreads();

  for (int t = 0; t < SEQ / 64; ++t) {
    const int cur = t & 1;
    const bool more = (t + 1) < SEQ / 64;
    uint4 kreg[2], vreg[2];
    if (more) {
      int k0 = (t + 1) * 64;
#pragma unroll
      for (int i = 0; i < 2; ++i) {
        int c = tid + i * 256;
        int row = c >> 3, sub = c & 7;
        kreg[i] = *reinterpret_cast<const uint4*>(&Kg[kbase + (size_t)(k0 + row) * D_MODEL + sub * 8]);
        vreg[i] = *reinterpret_cast<const uint4*>(&VT[vbase + (size_t)row * SEQ + k0 + sub * 8]);
      }
    }

    // QK^T swapped: A=K (row=key), B=Q (col=q)
    f32x4 st[4];
#pragma unroll
    for (int n = 0; n < 4; ++n) {
      short8 a0 = *reinterpret_cast<const short8*>(&Ks[cur][n * 16 + qi][g * 8]);
      short8 a1 = *reinterpret_cast<const short8*>(&Ks[cur][n * 16 + qi][32 + g * 8]);
      f32x4 z = (f32x4){0.f, 0.f, 0.f, 0.f};
      z = __builtin_amdgcn_mfma_f32_16x16x32_bf16(a0, qfr[0], z, 0, 0, 0);
      z = __builtin_amdgcn_mfma_f32_16x16x32_bf16(a1, qfr[1], z, 0, 0, 0);
      st[n] = z;
    }

    // online softmax: lane owns one query, 16 raw scores
    float m = st[0][0];
#pragma unroll
    for (int n = 0; n < 4; ++n)
#pragma unroll
      for (int r = 0; r < 4; ++r) m = fmaxf(m, st[n][r]);
    m = fmaxf(m, __shfl_xor(m, 16));
    m = fmaxf(m, __shfl_xor(m, 32));
    float nm = fmaxf(runM, m);
    float al = __expf((runM - nm) * 0.125f);
    float l = 0.f;
#pragma unroll
    for (int n = 0; n < 4; ++n)
#pragma unroll
      for (int r = 0; r < 4; ++r) {
        float p = __expf((st[n][r] - nm) * 0.125f);
        st[n][r] = p;
        l += p;
      }
    l += __shfl_xor(l, 16);
    l += __shfl_xor(l, 32);
    runL = runL * al + l;
    runM = nm;

    // P -> bf16 packed (lane-local PV B-fragments)
    unsigned pk[4][2];
#pragma unroll
    for (int n = 0; n < 4; ++n) {
      pk[n][0] = pack2(st[n][0], st[n][1]);
      pk[n][1] = pack2(st[n][2], st[n][3]);
    }

    // write next tile to the other LDS buffer (loads already in flight)
    if (more) {
      const int nb = cur ^ 1;
#pragma unroll
      for (int i = 0; i < 2; ++i) {
        int c = tid + i * 256;
        int row = c >> 3, sub = c & 7;
        *reinterpret_cast<uint4*>(&Ks[nb][row][sub * 8]) = kreg[i];
        int posA = 32 * (sub >> 2) + 16 * (sub & 1) + 4 * ((sub >> 1) & 1);
        *reinterpret_cast<uint2*>(&Vs[nb][row][posA])     = make_uint2(vreg[i].x, vreg[i].y);
        *reinterpret_cast<uint2*>(&Vs[nb][row][posA + 8]) = make_uint2(vreg[i].z, vreg[i].w);
      }
    }

    // rescale O
#pragma unroll
    for (int db = 0; db < 4; ++db)
#pragma unroll
      for (int r = 0; r < 4; ++r) o[db][r] *= al;

    // PV: O^T[d][q] += V^T[d][pi(k)] * P^T[pi(k)][q]
    short8 pb0 = mk_frag(pk[0][0], pk[0][1], pk[1][0], pk[1][1]);
    short8 pb1 = mk_frag(pk[2][0], pk[2][1], pk[3][0], pk[3][1]);
#pragma unroll
    for (int db = 0; db < 4; ++db) {
      short8 va0 = *reinterpret_cast<const short8*>(&Vs[cur][db * 16 + qi][g * 8]);
      short8 va1 = *reinterpret_cast<const short8*>(&Vs[cur][db * 16 + qi][32 + g * 8]);
      o[db] = __builtin_amdgcn_mfma_f32_16x16x32_bf16(va0, pb0, o[db], 0, 0, 0);
      o[db] = __builtin_amdgcn_mfma_f32_16x16x32_bf16(va1, pb1, o[db], 0, 0, 0);
    }

    __syncthreads();
  }

  // epilogue: transpose O^T -> rows via dead K buffer, then coalesced store
  short (*Os)[72] = reinterpret_cast<short(*)[72]>(&Ks[0][0][0]);
  float inv = 1.f / runL;
#pragma unroll
  for (int db = 0; db < 4; ++db)
#pragma unroll
    for (int r = 0; r < 4; ++r)
      Os[wave * 16 + qi][db * 16 + g * 4 + r] = bf16_of(o[db][r] * inv);
  __syncthreads();
#pragma unroll
  for (int i = 0; i < 2; ++i) {
    int c = tid + i * 256;
    int row = c >> 3, sub = c & 7;
    *reinterpret_cast<uint4*>(&Oc[((size_t)b * SEQ + q0 + row) * D_MODEL + h * HDIM + sub * 8]) =
        *reinterpret_cast<const uint4*>(&Os[row][sub * 8]);
  }
}

// ---------------- launch ----------------
extern "C" void kernel_launch(void* const* d_in, const int* in_sizes, int n_in,
                              void* d_out, int out_size, void* d_ws, size_t ws_size,
                              hipStream_t stream)
{
  const float* q  = (const float*)d_in[0];
  const float* k  = (const float*)d_in[1];
  const float* v  = (const float*)d_in[2];
  const float* Wq = (const float*)d_in[3];
  const float* bq = (const float*)d_in[4];
  const float* Wk = (const float*)d_in[5];
  const float* bk = (const float*)d_in[6];
  const float* Wv = (const float*)d_in[7];
  const float* bv = (const float*)d_in[8];
  const float* Wo = (const float*)d_in[9];
  const float* bo = (const float*)d_in[10];

  char* ws = (char*)d_ws;
  const size_t MB = 1ull << 20;
  short* Wq_b = (short*)(ws + 0 * MB);
  short* Wk_b = (short*)(ws + 2 * MB);
  short* Wv_b = (short*)(ws + 4 * MB);
  short* Wo_b = (short*)(ws + 6 * MB);
  short* Qb   = (short*)(ws + 8 * MB);
  short* Kb   = (short*)(ws + 24 * MB);
  short* Vb   = (short*)(ws + 40 * MB);
  short* VTb  = (short*)(ws + 56 * MB);
  short* Ac   = (short*)(ws + 40 * MB);   // aliases Vb (dead after transpose)

  const int M = BATCH * SEQ;
  int n4w = (D_MODEL * D_MODEL) / 4;
  cvt_f32_bf16<<<512, 256, 0, stream>>>(Wq, Wq_b, n4w);
  cvt_f32_bf16<<<512, 256, 0, stream>>>(Wk, Wk_b, n4w);
  cvt_f32_bf16<<<512, 256, 0, stream>>>(Wv, Wv_b, n4w);
  cvt_f32_bf16<<<512, 256, 0, stream>>>(Wo, Wo_b, n4w);

  dim3 gg(D_MODEL / 128, M / 128);
  gemm_bt<true, false><<<gg, 256, 0, stream>>>(q, Wq_b, bq, Qb, M, D_MODEL, D_MODEL);
  gemm_bt<true, false><<<gg, 256, 0, stream>>>(k, Wk_b, bk, Kb, M, D_MODEL, D_MODEL);
  gemm_bt<true, false><<<gg, 256, 0, stream>>>(v, Wv_b, bv, Vb, M, D_MODEL, D_MODEL);

  transpose_v<<<dim3(SEQ / 64, BATCH * NHEADS), 256, 0, stream>>>(Vb, VTb);

  attn_fwd<<<dim3(SEQ / 64, BATCH * NHEADS), 256, 0, stream>>>(Qb, Kb, VTb, Ac);

  gemm_bt<false, true><<<gg, 256, 0, stream>>>(Ac, Wo_b, bo, (float*)d_out, M, D_MODEL, D_MODEL);
}